// Round 12
// baseline (77.335 us; speedup 1.0000x reference)
//
#include <hip/hip_runtime.h>
#include <math.h>

#define B_    4
#define TDEC  512
#define TENC  1024
#define H_    128
#define DT    4

// exp(2*enc) transposed+packed: [b][g:32][e:1024][j:4]  (lane-contiguous in e)
__device__ float g_ebp[(size_t)B_ * 32 * TENC * 4];   // 2 MB
// per (row-tile rt, g): [V4(4), Ea_d0(4), Ea_d1(4), Ea_d2(4), Ea_d3(4)] = 20 f
__device__ float g_eav[(size_t)B_ * 128 * 32 * 20];   // 1.3 MB
__device__ float g_sv[1];                             // sum(V_w)

struct EAV { float4 v4, ea0, ea1, ea2, ea3; };
union F4 { float4 v; float f[4]; };

// z<4: transpose enc, store exp(2*enc) -> g_ebp.   z==4: Ea rows + V pack + SV.
__global__ __launch_bounds__(256) void prep_kernel(const float* __restrict__ enc,
                                                   const float* __restrict__ dec,
                                                   const float* __restrict__ Ww,
                                                   const float* __restrict__ Wb,
                                                   const float* __restrict__ Vw) {
    const int z = blockIdx.z;
    const int tx = threadIdx.x, ty = threadIdx.y;
    if (z < B_) {
        __shared__ float tile[32][33];               // [e-local][h-local]
        const int e0 = blockIdx.x * 32, h0 = blockIdx.y * 32, b = z;
        const float* ep = enc + (size_t)b * TENC * H_;
        #pragma unroll
        for (int j = 0; j < 32; j += 8)
            tile[ty + j][tx] = ep[(size_t)(e0 + ty + j) * H_ + h0 + tx];
        __syncthreads();
        // thread (tx,ty): e = e0+tx, g = h0/4+ty -> one float4 store of exp(2x)
        const int g = (h0 >> 2) + ty, e = e0 + tx;
        float4 o;
        o.x = __expf(2.f * tile[tx][4 * ty + 0]);
        o.y = __expf(2.f * tile[tx][4 * ty + 1]);
        o.z = __expf(2.f * tile[tx][4 * ty + 2]);
        o.w = __expf(2.f * tile[tx][4 * ty + 3]);
        *(float4*)&g_ebp[(((size_t)b * 32 + g) * TENC + e) * 4] = o;
    } else {
        // 128 blocks x 16 rows: Ea = exp(2*(dec @ Ww^T + Wb)); pack Ea & V
        __shared__ float ds[16][H_];
        const int t = ty * 32 + tx;
        const int blk = blockIdx.y * 32 + blockIdx.x;      // 0..127
        const int R0 = blk * 16;
        #pragma unroll
        for (int i = 0; i < 8; ++i) {
            const int f = t + 256 * i;
            ds[f >> 7][f & 127] = dec[(size_t)R0 * H_ + f];
        }
        __syncthreads();
        const int k = t & 127, dd = t >> 7;
        const float* wr = Ww + (size_t)k * H_;
        float s[8];
        #pragma unroll
        for (int j = 0; j < 8; ++j) s[j] = 0.f;
        for (int h = 0; h < H_; h += 4) {
            const float4 w4 = *(const float4*)(wr + h);
            #pragma unroll
            for (int j = 0; j < 8; ++j) {
                const float4 d4 = *(const float4*)&ds[dd + 2 * j][h];
                s[j] = fmaf(w4.x, d4.x, s[j]);
                s[j] = fmaf(w4.y, d4.y, s[j]);
                s[j] = fmaf(w4.z, d4.z, s[j]);
                s[j] = fmaf(w4.w, d4.w, s[j]);
            }
        }
        const float wb = Wb[k], vw = Vw[k];
        const int g = k >> 2, jj = k & 3;
        #pragma unroll
        for (int j = 0; j < 8; ++j) {
            const int rl = dd + 2 * j;          // row within 16-row block
            const int R = R0 + rl;
            const float ea = __expf(2.f * (s[j] + wb));
            g_eav[((size_t)(R >> 2) * 32 + g) * 20 + 4 + (R & 3) * 4 + jj] = ea;
        }
        if (dd == 0) {
            #pragma unroll
            for (int r = 0; r < 4; ++r)
                g_eav[((size_t)((R0 >> 2) + r) * 32 + g) * 20 + jj] = vw;
        }
        if (blk == 0) {
            __shared__ float svp[2];
            if (t < 128) {
                float x = vw;
                #pragma unroll
                for (int off = 32; off; off >>= 1) x += __shfl_xor(x, off);
                if ((t & 63) == 0) svp[t >> 6] = x;
            }
            __syncthreads();
            if (t == 0) g_sv[0] = svp[0] + svp[1];
        }
    }
}

// 4-h fraction combine: sum_i V_i/p_i with p_i = 1 + Ea_i*Eb_i; one rcp.
__device__ __forceinline__ float term4(const float4 ea, const float4 v4,
                                       const F4 te, float acc) {
    const float p0 = fmaf(ea.x, te.f[0], 1.f);
    const float p1 = fmaf(ea.y, te.f[1], 1.f);
    const float p2 = fmaf(ea.z, te.f[2], 1.f);
    const float p3 = fmaf(ea.w, te.f[3], 1.f);
    const float p01 = p0 * p1, p23 = p2 * p3;
    const float a  = fmaf(v4.y, p0, v4.x * p1);
    const float bq = fmaf(v4.w, p2, v4.z * p3);
    const float num = fmaf(bq, p01, a * p23);
    return fmaf(num, __builtin_amdgcn_rcpf(p01 * p23), acc);
}

#define DALL(S, TE)                         \
    acc0 = term4(S.ea0, S.v4, TE, acc0);    \
    acc1 = term4(S.ea1, S.v4, TE, acc1);    \
    acc2 = term4(S.ea2, S.v4, TE, acc2);    \
    acc3 = term4(S.ea3, S.v4, TE, acc3);

#if defined(__has_builtin)
#if __has_builtin(__builtin_amdgcn_global_load_lds)
#define HAVE_DMA 1
#endif
#endif

// Stage te plane g (16 KB) into slot (g&1) of pair-buffer `pb`.
// DMA: no dest VGPR -> nothing to sink; LDS dest wave-uniform + lane*16.
#ifdef HAVE_DMA
#define STAGEP(pb, g) do {                                                     \
    const float* gs_ = tep + (size_t)(g) * 4096 + t * 4;                       \
    float* ls_ = (pb) + ((g) & 1) * 4096 + (t >> 6) * 256;                     \
    __builtin_amdgcn_global_load_lds(                                          \
        (__attribute__((address_space(1))) void*)gs_,                          \
        (__attribute__((address_space(3))) void*)ls_, 16, 0, 0);               \
} while (0)
#else
#define STAGEP(pb, g) do {                                                     \
    const float* gs_ = tep + (size_t)(g) * 4096 + t * 4;                       \
    float* ls_ = (pb) + ((g) & 1) * 4096 + t * 4;                              \
    *(float4*)ls_ = *(const float4*)gs_;                                       \
} while (0)
#endif

// Fused: score + softmax(sum-only) + context + write.  Block = 1 row-tile,
// 1024 threads (1 e each), grid 512 -> 2 blocks/CU, 32 waves/CU.
// te staged via global_load_lds, double-buffered in g-pairs (16 barriers).
// LDS reuse: [0,32K) = pair-buf A / sc+wsum+rsum;  [32K,64K) = pair-buf B / part.
__global__ __launch_bounds__(1024, 8) void fused_kernel(const float* __restrict__ enc,
                                                        float* __restrict__ out) {
    __shared__ __align__(16) char shbuf[65536];
    float* pb0 = (float*)shbuf;
    float* pb1 = (float*)(shbuf + 32768);
    float* sc   = (float*)shbuf;                    // [d][e] 16 KB (phase >= 2)
    float* wsum = (float*)(shbuf + 16384);          // [16][4]
    float* rsum = (float*)(shbuf + 16384 + 256);    // [4]
    float2* part = (float2*)(shbuf + 32768);        // [16][4][64] (phase 3)

    const int t = threadIdx.x;
    // XCD swizzle: XCD x gets a contiguous 64-row-tile chunk of one batch
    const int bid = blockIdx.x;
    const int rt = (bid & 7) * 64 + (bid >> 3);
    const int b = rt >> 7;
    const int R0 = rt * DT;
    const EAV* epk = (const EAV*)g_eav + (size_t)rt * 32;
    const float* tep = g_ebp + (size_t)b * 32 * 4096;
    const float sv = g_sv[0];

    // --- Phase 1: scores; te via DMA-staged LDS double buffer ---
    float acc0 = 0.f, acc1 = 0.f, acc2 = 0.f, acc3 = 0.f;

    STAGEP(pb0, 0);
    STAGEP(pb0, 1);
    __syncthreads();

    #pragma unroll 2
    for (int k = 0; k < 16; ++k) {
        float* cur = (k & 1) ? pb1 : pb0;
        float* nxt = (k & 1) ? pb0 : pb1;
        if (k < 15) {
            STAGEP(nxt, 2 * k + 2);
            STAGEP(nxt, 2 * k + 3);
        }
        const EAV A  = epk[2 * k];
        const EAV Bv = epk[2 * k + 1];
        F4 ta; ta.v = *(const float4*)(cur + t * 4);
        F4 tb; tb.v = *(const float4*)(cur + 4096 + t * 4);
        DALL(A, ta);
        DALL(Bv, tb);
        __syncthreads();   // drains this iter's DMA; frees cur for overwrite
    }

    // --- Phase 2: p = exp(score); stash + per-wave partial sums ---
    const float q0 = __expf(fmaf(-2.f, acc0, sv));
    const float q1 = __expf(fmaf(-2.f, acc1, sv));
    const float q2 = __expf(fmaf(-2.f, acc2, sv));
    const float q3 = __expf(fmaf(-2.f, acc3, sv));
    sc[0 * TENC + t] = q0; sc[1 * TENC + t] = q1;
    sc[2 * TENC + t] = q2; sc[3 * TENC + t] = q3;

    float s0 = q0, s1 = q1, s2 = q2, s3 = q3;
    #pragma unroll
    for (int off = 32; off; off >>= 1) {
        s0 += __shfl_xor(s0, off);
        s1 += __shfl_xor(s1, off);
        s2 += __shfl_xor(s2, off);
        s3 += __shfl_xor(s3, off);
    }
    {
        const int w = t >> 6, lane = t & 63;
        if (lane == 0) {
            wsum[w * 4 + 0] = s0; wsum[w * 4 + 1] = s1;
            wsum[w * 4 + 2] = s2; wsum[w * 4 + 3] = s3;
        }
    }
    __syncthreads();
    if (t < 64) {                            // lane = w'*4 + d
        float x = wsum[(t >> 2) * 4 + (t & 3)];
        #pragma unroll
        for (int off = 4; off < 64; off <<= 1) x += __shfl_xor(x, off);
        if (t < 4) rsum[t] = x;
    }

    // --- Phase 3: context partials; thread = (q = e-slice of 64, h2) ---
    {
        const int q = t >> 6, h2 = t & 63;
        const float* eb = enc + (size_t)b * TENC * H_ + 2 * h2;
        float2 a0 = {0.f, 0.f}, a1 = {0.f, 0.f}, a2 = {0.f, 0.f}, a3 = {0.f, 0.f};
        const int e0 = q * 64;
        for (int e = e0; e < e0 + 64; e += 4) {
            F4 u0, u1, u2, u3;
            u0.v = *(const float4*)&sc[0 * TENC + e];
            u1.v = *(const float4*)&sc[1 * TENC + e];
            u2.v = *(const float4*)&sc[2 * TENC + e];
            u3.v = *(const float4*)&sc[3 * TENC + e];
            #pragma unroll
            for (int j = 0; j < 4; ++j) {
                const float2 ev = *(const float2*)(eb + (size_t)(e + j) * H_);
                a0.x = fmaf(u0.f[j], ev.x, a0.x); a0.y = fmaf(u0.f[j], ev.y, a0.y);
                a1.x = fmaf(u1.f[j], ev.x, a1.x); a1.y = fmaf(u1.f[j], ev.y, a1.y);
                a2.x = fmaf(u2.f[j], ev.x, a2.x); a2.y = fmaf(u2.f[j], ev.y, a2.y);
                a3.x = fmaf(u3.f[j], ev.x, a3.x); a3.y = fmaf(u3.f[j], ev.y, a3.y);
            }
        }
        part[(q * 4 + 0) * 64 + h2] = a0; part[(q * 4 + 1) * 64 + h2] = a1;
        part[(q * 4 + 2) * 64 + h2] = a2; part[(q * 4 + 3) * 64 + h2] = a3;
    }
    __syncthreads();

    // --- Phase 4: merge 16 slices, divide, write ---
    if (t < 256) {
        const int d = t >> 6, h2 = t & 63;
        float2 s = {0.f, 0.f};
        #pragma unroll
        for (int q = 0; q < 16; ++q) {
            const float2 pp = part[(q * 4 + d) * 64 + h2];
            s.x += pp.x; s.y += pp.y;
        }
        const float rinv = __builtin_amdgcn_rcpf(rsum[d]);
        s.x *= rinv; s.y *= rinv;
        *(float2*)(out + (size_t)(R0 + d) * H_ + 2 * h2) = s;
    }
}

extern "C" void kernel_launch(void* const* d_in, const int* in_sizes, int n_in,
                              void* d_out, int out_size, void* d_ws, size_t ws_size,
                              hipStream_t stream) {
    const float* dec = (const float*)d_in[0];
    const float* enc = (const float*)d_in[1];
    const float* Ww  = (const float*)d_in[2];
    const float* Wb  = (const float*)d_in[3];
    const float* Vw  = (const float*)d_in[4];
    float* out = (float*)d_out;

    prep_kernel<<<dim3(TENC / 32, H_ / 32, B_ + 1), dim3(32, 8), 0, stream>>>(
        enc, dec, Ww, Wb, Vw);
    fused_kernel<<<dim3(B_ * 128), dim3(1024), 0, stream>>>(enc, out);
}

// Round 13
// 50.761 us; speedup vs baseline: 1.5235x; 1.5235x over previous
//
#include <hip/hip_runtime.h>
#include <math.h>

#define B_    4
#define TDEC  512
#define TENC  1024
#define H_    128
#define DT    4

// exp(2*enc) transposed+packed: [b][g:32][e:1024][j:4]  (lane-contiguous in e)
__device__ float g_ebp[(size_t)B_ * 32 * TENC * 4];   // 2 MB
// per (row-tile rt, g): [V4(4), Ea_d0(4), Ea_d1(4), Ea_d2(4), Ea_d3(4)] = 20 f
__device__ float g_eav[(size_t)B_ * 128 * 32 * 20];   // 1.3 MB
__device__ float g_sv[1];                             // sum(V_w)

struct EAV { float4 v4, ea0, ea1, ea2, ea3; };
union F4 { float4 v; float f[4]; };

// z<4: transpose enc, store exp(2*enc) -> g_ebp.   z==4: Ea rows + V pack + SV.
__global__ __launch_bounds__(256) void prep_kernel(const float* __restrict__ enc,
                                                   const float* __restrict__ dec,
                                                   const float* __restrict__ Ww,
                                                   const float* __restrict__ Wb,
                                                   const float* __restrict__ Vw) {
    const int z = blockIdx.z;
    const int tx = threadIdx.x, ty = threadIdx.y;
    if (z < B_) {
        __shared__ float tile[32][33];               // [e-local][h-local]
        const int e0 = blockIdx.x * 32, h0 = blockIdx.y * 32, b = z;
        const float* ep = enc + (size_t)b * TENC * H_;
        #pragma unroll
        for (int j = 0; j < 32; j += 8)
            tile[ty + j][tx] = ep[(size_t)(e0 + ty + j) * H_ + h0 + tx];
        __syncthreads();
        // thread (tx,ty): e = e0+tx, g = h0/4+ty -> one float4 store of exp(2x)
        const int g = (h0 >> 2) + ty, e = e0 + tx;
        float4 o;
        o.x = __expf(2.f * tile[tx][4 * ty + 0]);
        o.y = __expf(2.f * tile[tx][4 * ty + 1]);
        o.z = __expf(2.f * tile[tx][4 * ty + 2]);
        o.w = __expf(2.f * tile[tx][4 * ty + 3]);
        *(float4*)&g_ebp[(((size_t)b * 32 + g) * TENC + e) * 4] = o;
    } else {
        // 128 blocks x 16 rows: Ea = exp(2*(dec @ Ww^T + Wb)); pack Ea & V
        __shared__ float ds[16][H_];
        const int t = ty * 32 + tx;
        const int blk = blockIdx.y * 32 + blockIdx.x;      // 0..127
        const int R0 = blk * 16;
        #pragma unroll
        for (int i = 0; i < 8; ++i) {
            const int f = t + 256 * i;
            ds[f >> 7][f & 127] = dec[(size_t)R0 * H_ + f];
        }
        __syncthreads();
        const int k = t & 127, dd = t >> 7;
        const float* wr = Ww + (size_t)k * H_;
        float s[8];
        #pragma unroll
        for (int j = 0; j < 8; ++j) s[j] = 0.f;
        for (int h = 0; h < H_; h += 4) {
            const float4 w4 = *(const float4*)(wr + h);
            #pragma unroll
            for (int j = 0; j < 8; ++j) {
                const float4 d4 = *(const float4*)&ds[dd + 2 * j][h];
                s[j] = fmaf(w4.x, d4.x, s[j]);
                s[j] = fmaf(w4.y, d4.y, s[j]);
                s[j] = fmaf(w4.z, d4.z, s[j]);
                s[j] = fmaf(w4.w, d4.w, s[j]);
            }
        }
        const float wb = Wb[k], vw = Vw[k];
        const int g = k >> 2, jj = k & 3;
        #pragma unroll
        for (int j = 0; j < 8; ++j) {
            const int rl = dd + 2 * j;          // row within 16-row block
            const int R = R0 + rl;
            const float ea = __expf(2.f * (s[j] + wb));
            g_eav[((size_t)(R >> 2) * 32 + g) * 20 + 4 + (R & 3) * 4 + jj] = ea;
        }
        if (dd == 0) {
            #pragma unroll
            for (int r = 0; r < 4; ++r)
                g_eav[((size_t)((R0 >> 2) + r) * 32 + g) * 20 + jj] = vw;
        }
        if (blk == 0) {
            __shared__ float svp[2];
            if (t < 128) {
                float x = vw;
                #pragma unroll
                for (int off = 32; off; off >>= 1) x += __shfl_xor(x, off);
                if ((t & 63) == 0) svp[t >> 6] = x;
            }
            __syncthreads();
            if (t == 0) g_sv[0] = svp[0] + svp[1];
        }
    }
}

// 4-h fraction combine: sum_i V_i/p_i with p_i = 1 + Ea_i*Eb_i; one rcp.
__device__ __forceinline__ float term4(const float4 ea, const float4 v4,
                                       const F4 te, float acc) {
    const float p0 = fmaf(ea.x, te.f[0], 1.f);
    const float p1 = fmaf(ea.y, te.f[1], 1.f);
    const float p2 = fmaf(ea.z, te.f[2], 1.f);
    const float p3 = fmaf(ea.w, te.f[3], 1.f);
    const float p01 = p0 * p1, p23 = p2 * p3;
    const float a  = fmaf(v4.y, p0, v4.x * p1);
    const float bq = fmaf(v4.w, p2, v4.z * p3);
    const float num = fmaf(bq, p01, a * p23);
    return fmaf(num, __builtin_amdgcn_rcpf(p01 * p23), acc);
}

#define DALL(S, TE)                         \
    acc0 = term4(S.ea0, S.v4, TE, acc0);    \
    acc1 = term4(S.ea1, S.v4, TE, acc1);    \
    acc2 = term4(S.ea2, S.v4, TE, acc2);    \
    acc3 = term4(S.ea3, S.v4, TE, acc3);

// Fused: score + softmax(sum-only) + context + write.  Block = 1 row-tile
// (4 rows), 1024 threads (thread owns 1 e); grid 512 -> 2 blocks/CU,
// 8 waves/SIMD.  Phase-1 loads batched 8-deep for MLP; XCD-swizzled grid.
__global__ __launch_bounds__(1024, 8) void fused_kernel(const float* __restrict__ enc,
                                                        float* __restrict__ out) {
    __shared__ float sc[DT][TENC];          // p = exp(score)      (16 KB)
    __shared__ float2 part[16][DT][64];     // context partials    (32 KB)
    __shared__ float wsum[16][DT];
    __shared__ float rsum[DT];

    const int t = threadIdx.x;
    // XCD-locality swizzle: XCD x (= bid%8) gets contiguous row-tiles
    // [x*64, x*64+64) -> per-XCD working set ~1.2 MB < 4 MB L2.
    const int bid = blockIdx.x;
    const int rt = (bid & 7) * 64 + (bid >> 3);
    const int b = rt >> 7;
    const int R0 = rt * DT;
    const EAV* epk = (const EAV*)g_eav + (size_t)rt * 32;
    const float* teb = g_ebp + (size_t)b * 32 * (TENC * 4) + t * 4;
    const float sv = g_sv[0];

    // --- Phase 1: scores; te loads issued in batches of 8 (MLP), then math ---
    float acc0 = 0.f, acc1 = 0.f, acc2 = 0.f, acc3 = 0.f;

    for (int kb = 0; kb < 4; ++kb) {
        F4 te[8];
        #pragma unroll
        for (int i = 0; i < 8; ++i)
            te[i].v = *(const float4*)(teb + (size_t)(kb * 8 + i) * (TENC * 4));
        #pragma unroll
        for (int i = 0; i < 8; ++i) {
            const EAV S = epk[kb * 8 + i];
            DALL(S, te[i]);
        }
    }

    // --- Phase 2: p = exp(score); stash + per-wave partial sums ---
    const float q0 = __expf(fmaf(-2.f, acc0, sv));
    const float q1 = __expf(fmaf(-2.f, acc1, sv));
    const float q2 = __expf(fmaf(-2.f, acc2, sv));
    const float q3 = __expf(fmaf(-2.f, acc3, sv));
    sc[0][t] = q0; sc[1][t] = q1; sc[2][t] = q2; sc[3][t] = q3;

    float s0 = q0, s1 = q1, s2 = q2, s3 = q3;
    #pragma unroll
    for (int off = 32; off; off >>= 1) {
        s0 += __shfl_xor(s0, off);
        s1 += __shfl_xor(s1, off);
        s2 += __shfl_xor(s2, off);
        s3 += __shfl_xor(s3, off);
    }
    {
        const int w = t >> 6, lane = t & 63;
        if (lane == 0) { wsum[w][0] = s0; wsum[w][1] = s1; wsum[w][2] = s2; wsum[w][3] = s3; }
    }
    __syncthreads();
    if (t < 64) {                            // lane = w'*4 + d
        float x = wsum[t >> 2][t & 3];
        #pragma unroll
        for (int off = 4; off < 64; off <<= 1) x += __shfl_xor(x, off);
        if (t < 4) rsum[t] = x;
    }

    // --- Phase 3: context partials; thread = (q = e-slice of 64, h2) ---
    {
        const int q = t >> 6, h2 = t & 63;
        const float* eb = enc + (size_t)b * TENC * H_ + 2 * h2;
        float2 a0 = {0.f, 0.f}, a1 = {0.f, 0.f}, a2 = {0.f, 0.f}, a3 = {0.f, 0.f};
        const int e0 = q * 64;
        for (int e = e0; e < e0 + 64; e += 4) {
            F4 u0, u1, u2, u3;
            u0.v = *(const float4*)&sc[0][e];
            u1.v = *(const float4*)&sc[1][e];
            u2.v = *(const float4*)&sc[2][e];
            u3.v = *(const float4*)&sc[3][e];
            #pragma unroll
            for (int j = 0; j < 4; ++j) {
                const float2 ev = *(const float2*)(eb + (size_t)(e + j) * H_);
                a0.x = fmaf(u0.f[j], ev.x, a0.x); a0.y = fmaf(u0.f[j], ev.y, a0.y);
                a1.x = fmaf(u1.f[j], ev.x, a1.x); a1.y = fmaf(u1.f[j], ev.y, a1.y);
                a2.x = fmaf(u2.f[j], ev.x, a2.x); a2.y = fmaf(u2.f[j], ev.y, a2.y);
                a3.x = fmaf(u3.f[j], ev.x, a3.x); a3.y = fmaf(u3.f[j], ev.y, a3.y);
            }
        }
        part[q][0][h2] = a0; part[q][1][h2] = a1;
        part[q][2][h2] = a2; part[q][3][h2] = a3;
    }
    __syncthreads();

    // --- Phase 4: merge 16 slices, divide, write ---
    if (t < 256) {
        const int d = t >> 6, h2 = t & 63;
        float2 s = {0.f, 0.f};
        #pragma unroll
        for (int q = 0; q < 16; ++q) {
            const float2 pp = part[q][d][h2];
            s.x += pp.x; s.y += pp.y;
        }
        const float rinv = __builtin_amdgcn_rcpf(rsum[d]);
        s.x *= rinv; s.y *= rinv;
        *(float2*)(out + (size_t)(R0 + d) * H_ + 2 * h2) = s;
    }
}

extern "C" void kernel_launch(void* const* d_in, const int* in_sizes, int n_in,
                              void* d_out, int out_size, void* d_ws, size_t ws_size,
                              hipStream_t stream) {
    const float* dec = (const float*)d_in[0];
    const float* enc = (const float*)d_in[1];
    const float* Ww  = (const float*)d_in[2];
    const float* Wb  = (const float*)d_in[3];
    const float* Vw  = (const float*)d_in[4];
    float* out = (float*)d_out;

    prep_kernel<<<dim3(TENC / 32, H_ / 32, B_ + 1), dim3(32, 8), 0, stream>>>(
        enc, dec, Ww, Wb, Vw);
    fused_kernel<<<dim3(B_ * 128), dim3(1024), 0, stream>>>(enc, out);
}

// Round 15
// 44.449 us; speedup vs baseline: 1.7398x; 1.1420x over previous
//
#include <hip/hip_runtime.h>
#include <math.h>

#define B_    4
#define TDEC  512
#define TENC  1024
#define H_    128
#define DT    4

// exp(2*enc) transposed, fp16-packed: [b][gp:16][e:1024][j:8]
// (gp = pair of 4-h groups; one dwordx4 per thread = 8 fp16 = 2 g-planes)
__device__ _Float16 g_ebp[(size_t)B_ * 16 * TENC * 8];   // 1 MB
// fp16 copy of enc in natural layout [b][e][h] (for the context phase)
__device__ _Float16 g_ench[(size_t)B_ * TENC * H_];      // 1 MB
// per (row-tile rt, g): [V4(4), Ea_d0(4), Ea_d1(4), Ea_d2(4), Ea_d3(4)] = 20 f
__device__ float g_eav[(size_t)B_ * 128 * 32 * 20];      // 1.3 MB
__device__ float g_sv[1];                                // sum(V_w)

struct EAV { float4 v4, ea0, ea1, ea2, ea3; };
union F4 { float4 v; float f[4]; };
union H8 { float4 v; _Float16 h[8]; };
union H4 { ushort4 u4; _Float16 h[4]; };
union H2 { unsigned int u; _Float16 h[2]; };

// z<4: transpose enc -> fp16 exp(2*enc) planes + fp16 enc copy.  z==4: Ea+V pack.
__global__ __launch_bounds__(256) void prep_kernel(const float* __restrict__ enc,
                                                   const float* __restrict__ dec,
                                                   const float* __restrict__ Ww,
                                                   const float* __restrict__ Wb,
                                                   const float* __restrict__ Vw) {
    const int z = blockIdx.z;
    const int tx = threadIdx.x, ty = threadIdx.y;
    if (z < B_) {
        __shared__ float tile[32][33];               // [e-local][h-local]
        const int e0 = blockIdx.x * 32, h0 = blockIdx.y * 32, b = z;
        const float* ep = enc + (size_t)b * TENC * H_;
        #pragma unroll
        for (int j = 0; j < 32; j += 8) {
            const float v = ep[(size_t)(e0 + ty + j) * H_ + h0 + tx];
            tile[ty + j][tx] = v;
            g_ench[(size_t)b * TENC * H_ + (size_t)(e0 + ty + j) * H_ + h0 + tx]
                = (_Float16)v;
        }
        __syncthreads();
        // thread (tx,ty): e = e0+tx, g = h0/4+ty -> 4 fp16 (half of a gp-plane)
        const int g = (h0 >> 2) + ty, e = e0 + tx;
        const int gp = g >> 1, hs = g & 1;
        H4 o;
        // clamp below fp16 inf (65504) to avoid inf -> NaN in the rcp chain
        o.h[0] = (_Float16)fminf(__expf(2.f * tile[tx][4 * ty + 0]), 60000.f);
        o.h[1] = (_Float16)fminf(__expf(2.f * tile[tx][4 * ty + 1]), 60000.f);
        o.h[2] = (_Float16)fminf(__expf(2.f * tile[tx][4 * ty + 2]), 60000.f);
        o.h[3] = (_Float16)fminf(__expf(2.f * tile[tx][4 * ty + 3]), 60000.f);
        *(ushort4*)&g_ebp[((((size_t)b * 16 + gp) * TENC) + e) * 8 + hs * 4] = o.u4;
    } else {
        // 128 blocks x 16 rows: Ea = exp(2*(dec @ Ww^T + Wb)); pack Ea & V
        __shared__ float ds[16][H_];
        const int t = ty * 32 + tx;
        const int blk = blockIdx.y * 32 + blockIdx.x;      // 0..127
        const int R0 = blk * 16;
        #pragma unroll
        for (int i = 0; i < 8; ++i) {
            const int f = t + 256 * i;
            ds[f >> 7][f & 127] = dec[(size_t)R0 * H_ + f];
        }
        __syncthreads();
        const int k = t & 127, dd = t >> 7;
        const float* wr = Ww + (size_t)k * H_;
        float s[8];
        #pragma unroll
        for (int j = 0; j < 8; ++j) s[j] = 0.f;
        for (int h = 0; h < H_; h += 4) {
            const float4 w4 = *(const float4*)(wr + h);
            #pragma unroll
            for (int j = 0; j < 8; ++j) {
                const float4 d4 = *(const float4*)&ds[dd + 2 * j][h];
                s[j] = fmaf(w4.x, d4.x, s[j]);
                s[j] = fmaf(w4.y, d4.y, s[j]);
                s[j] = fmaf(w4.z, d4.z, s[j]);
                s[j] = fmaf(w4.w, d4.w, s[j]);
            }
        }
        const float wb = Wb[k], vw = Vw[k];
        const int g = k >> 2, jj = k & 3;
        #pragma unroll
        for (int j = 0; j < 8; ++j) {
            const int rl = dd + 2 * j;          // row within 16-row block
            const int R = R0 + rl;
            const float ea = __expf(2.f * (s[j] + wb));
            g_eav[((size_t)(R >> 2) * 32 + g) * 20 + 4 + (R & 3) * 4 + jj] = ea;
        }
        if (dd == 0) {
            #pragma unroll
            for (int r = 0; r < 4; ++r)
                g_eav[((size_t)((R0 >> 2) + r) * 32 + g) * 20 + jj] = vw;
        }
        if (blk == 0) {
            __shared__ float svp[2];
            if (t < 128) {
                float x = vw;
                #pragma unroll
                for (int off = 32; off; off >>= 1) x += __shfl_xor(x, off);
                if ((t & 63) == 0) svp[t >> 6] = x;
            }
            __syncthreads();
            if (t == 0) g_sv[0] = svp[0] + svp[1];
        }
    }
}

// 4-h fraction combine: sum_i V_i/p_i with p_i = 1 + Ea_i*Eb_i; one rcp.
__device__ __forceinline__ float term4(const float4 ea, const float4 v4,
                                       const F4 te, float acc) {
    const float p0 = fmaf(ea.x, te.f[0], 1.f);
    const float p1 = fmaf(ea.y, te.f[1], 1.f);
    const float p2 = fmaf(ea.z, te.f[2], 1.f);
    const float p3 = fmaf(ea.w, te.f[3], 1.f);
    const float p01 = p0 * p1, p23 = p2 * p3;
    const float a  = fmaf(v4.y, p0, v4.x * p1);
    const float bq = fmaf(v4.w, p2, v4.z * p3);
    const float num = fmaf(bq, p01, a * p23);
    return fmaf(num, __builtin_amdgcn_rcpf(p01 * p23), acc);
}

#define DALL(S, TE)                         \
    acc0 = term4(S.ea0, S.v4, TE, acc0);    \
    acc1 = term4(S.ea1, S.v4, TE, acc1);    \
    acc2 = term4(S.ea2, S.v4, TE, acc2);    \
    acc3 = term4(S.ea3, S.v4, TE, acc3);

// Fused: score + softmax(sum-only) + context + write.  Block = 1 row-tile
// (4 rows), 1024 threads (thread owns 1 e); grid 512, XCD-swizzled.
// Phase-1 te loads: 16 dwordx4 (fp16x8 = 2 g-planes each) instead of 32.
__global__ __launch_bounds__(1024, 8) void fused_kernel(float* __restrict__ out) {
    __shared__ float sc[DT][TENC];          // p = exp(score)      (16 KB)
    __shared__ float2 part[16][DT][64];     // context partials    (32 KB)
    __shared__ float wsum[16][DT];
    __shared__ float rsum[DT];

    const int t = threadIdx.x;
    // XCD-locality swizzle: XCD x (= bid%8) gets contiguous row-tiles
    const int bid = blockIdx.x;
    const int rt = (bid & 7) * 64 + (bid >> 3);
    const int b = rt >> 7;
    const int R0 = rt * DT;
    const EAV* epk = (const EAV*)g_eav + (size_t)rt * 32;
    const _Float16* teb = g_ebp + (size_t)b * 16 * TENC * 8 + t * 8;
    const float sv = g_sv[0];

    // --- Phase 1: scores; 16 load events, 8 term4 per load ---
    float acc0 = 0.f, acc1 = 0.f, acc2 = 0.f, acc3 = 0.f;

    for (int gp = 0; gp < 16; ++gp) {
        H8 r;
        r.v = *(const float4*)(teb + (size_t)gp * (TENC * 8));
        F4 ta, tb;
        ta.f[0] = (float)r.h[0]; ta.f[1] = (float)r.h[1];
        ta.f[2] = (float)r.h[2]; ta.f[3] = (float)r.h[3];
        tb.f[0] = (float)r.h[4]; tb.f[1] = (float)r.h[5];
        tb.f[2] = (float)r.h[6]; tb.f[3] = (float)r.h[7];
        const EAV A  = epk[2 * gp];
        const EAV Bv = epk[2 * gp + 1];
        DALL(A, ta);
        DALL(Bv, tb);
    }

    // --- Phase 2: p = exp(score); stash + per-wave partial sums ---
    const float q0 = __expf(fmaf(-2.f, acc0, sv));
    const float q1 = __expf(fmaf(-2.f, acc1, sv));
    const float q2 = __expf(fmaf(-2.f, acc2, sv));
    const float q3 = __expf(fmaf(-2.f, acc3, sv));
    sc[0][t] = q0; sc[1][t] = q1; sc[2][t] = q2; sc[3][t] = q3;

    float s0 = q0, s1 = q1, s2 = q2, s3 = q3;
    #pragma unroll
    for (int off = 32; off; off >>= 1) {
        s0 += __shfl_xor(s0, off);
        s1 += __shfl_xor(s1, off);
        s2 += __shfl_xor(s2, off);
        s3 += __shfl_xor(s3, off);
    }
    {
        const int w = t >> 6, lane = t & 63;
        if (lane == 0) { wsum[w][0] = s0; wsum[w][1] = s1; wsum[w][2] = s2; wsum[w][3] = s3; }
    }
    __syncthreads();
    if (t < 64) {                            // lane = w'*4 + d
        float x = wsum[t >> 2][t & 3];
        #pragma unroll
        for (int off = 4; off < 64; off <<= 1) x += __shfl_xor(x, off);
        if (t < 4) rsum[t] = x;
    }

    // --- Phase 3: context partials from fp16 enc; thread = (e-slice q, h2) ---
    {
        const int q = t >> 6, h2 = t & 63;
        const _Float16* eb = g_ench + (size_t)b * TENC * H_ + 2 * h2;
        float2 a0 = {0.f, 0.f}, a1 = {0.f, 0.f}, a2 = {0.f, 0.f}, a3 = {0.f, 0.f};
        const int e0 = q * 64;
        for (int e = e0; e < e0 + 64; e += 4) {
            F4 u0, u1, u2, u3;
            u0.v = *(const float4*)&sc[0][e];
            u1.v = *(const float4*)&sc[1][e];
            u2.v = *(const float4*)&sc[2][e];
            u3.v = *(const float4*)&sc[3][e];
            #pragma unroll
            for (int j = 0; j < 4; ++j) {
                H2 hv; hv.u = *(const unsigned int*)(eb + (size_t)(e + j) * H_);
                const float ex = (float)hv.h[0], ey = (float)hv.h[1];
                a0.x = fmaf(u0.f[j], ex, a0.x); a0.y = fmaf(u0.f[j], ey, a0.y);
                a1.x = fmaf(u1.f[j], ex, a1.x); a1.y = fmaf(u1.f[j], ey, a1.y);
                a2.x = fmaf(u2.f[j], ex, a2.x); a2.y = fmaf(u2.f[j], ey, a2.y);
                a3.x = fmaf(u3.f[j], ex, a3.x); a3.y = fmaf(u3.f[j], ey, a3.y);
            }
        }
        part[q][0][h2] = a0; part[q][1][h2] = a1;
        part[q][2][h2] = a2; part[q][3][h2] = a3;
    }
    __syncthreads();

    // --- Phase 4: merge 16 slices, divide, write ---
    if (t < 256) {
        const int d = t >> 6, h2 = t & 63;
        float2 s = {0.f, 0.f};
        #pragma unroll
        for (int q = 0; q < 16; ++q) {
            const float2 pp = part[q][d][h2];
            s.x += pp.x; s.y += pp.y;
        }
        const float rinv = __builtin_amdgcn_rcpf(rsum[d]);
        s.x *= rinv; s.y *= rinv;
        *(float2*)(out + (size_t)(R0 + d) * H_ + 2 * h2) = s;
    }
}

extern "C" void kernel_launch(void* const* d_in, const int* in_sizes, int n_in,
                              void* d_out, int out_size, void* d_ws, size_t ws_size,
                              hipStream_t stream) {
    const float* dec = (const float*)d_in[0];
    const float* enc = (const float*)d_in[1];
    const float* Ww  = (const float*)d_in[2];
    const float* Wb  = (const float*)d_in[3];
    const float* Vw  = (const float*)d_in[4];
    float* out = (float*)d_out;

    prep_kernel<<<dim3(TENC / 32, H_ / 32, B_ + 1), dim3(32, 8), 0, stream>>>(
        enc, dec, Ww, Wb, Vw);
    fused_kernel<<<dim3(B_ * 128), dim3(1024), 0, stream>>>(out);
}

// Round 16
// 43.173 us; speedup vs baseline: 1.7913x; 1.0296x over previous
//
#include <hip/hip_runtime.h>
#include <math.h>

#define B_    4
#define TDEC  512
#define TENC  1024
#define H_    128
#define DT    4

typedef float f2 __attribute__((ext_vector_type(2)));

// exp(2*enc) transposed, fp16-packed: [b][gp:16][e:1024][j:8]
__device__ _Float16 g_ebp[(size_t)B_ * 16 * TENC * 8];   // 1 MB
// fp16 copy of enc in natural layout [b][e][h] (for the context phase)
__device__ _Float16 g_ench[(size_t)B_ * TENC * H_];      // 1 MB
// per (row-tile rt, g): [V4(4), then h-major ea: h0{d0..d3} .. h3{d0..d3}] = 20 f
__device__ float g_eav[(size_t)B_ * 128 * 32 * 20];      // 1.3 MB
__device__ float g_sv[1];                                // sum(V_w)

struct EAVP { float4 v4; f2 hd[8]; };    // hd[2h+0]=(ea_d0,ea_d1)_h, hd[2h+1]=(ea_d2,ea_d3)_h
union F4 { float4 v; float f[4]; };
union H8 { float4 v; _Float16 h[8]; };
union H4 { ushort4 u4; _Float16 h[4]; };
union H2 { unsigned int u; _Float16 h[2]; };

static __device__ __forceinline__ f2 bc(float x) { f2 r = {x, x}; return r; }

// z<4: transpose enc -> fp16 exp(2*enc) planes + fp16 enc copy.  z==4: Ea+V pack.
__global__ __launch_bounds__(256) void prep_kernel(const float* __restrict__ enc,
                                                   const float* __restrict__ dec,
                                                   const float* __restrict__ Ww,
                                                   const float* __restrict__ Wb,
                                                   const float* __restrict__ Vw) {
    const int z = blockIdx.z;
    const int tx = threadIdx.x, ty = threadIdx.y;
    if (z < B_) {
        __shared__ float tile[32][33];               // [e-local][h-local]
        const int e0 = blockIdx.x * 32, h0 = blockIdx.y * 32, b = z;
        const float* ep = enc + (size_t)b * TENC * H_;
        #pragma unroll
        for (int j = 0; j < 32; j += 8) {
            const float v = ep[(size_t)(e0 + ty + j) * H_ + h0 + tx];
            tile[ty + j][tx] = v;
            g_ench[(size_t)b * TENC * H_ + (size_t)(e0 + ty + j) * H_ + h0 + tx]
                = (_Float16)v;
        }
        __syncthreads();
        // thread (tx,ty): e = e0+tx, g = h0/4+ty -> 4 fp16 (half of a gp-plane)
        const int g = (h0 >> 2) + ty, e = e0 + tx;
        const int gp = g >> 1, hs = g & 1;
        H4 o;
        // clamp below fp16 inf to avoid inf -> NaN in the rcp chain
        o.h[0] = (_Float16)fminf(__expf(2.f * tile[tx][4 * ty + 0]), 60000.f);
        o.h[1] = (_Float16)fminf(__expf(2.f * tile[tx][4 * ty + 1]), 60000.f);
        o.h[2] = (_Float16)fminf(__expf(2.f * tile[tx][4 * ty + 2]), 60000.f);
        o.h[3] = (_Float16)fminf(__expf(2.f * tile[tx][4 * ty + 3]), 60000.f);
        *(ushort4*)&g_ebp[((((size_t)b * 16 + gp) * TENC) + e) * 8 + hs * 4] = o.u4;
    } else {
        // 128 blocks x 16 rows: Ea = exp(2*(dec @ Ww^T + Wb)); pack Ea & V
        __shared__ float ds[16][H_];
        const int t = ty * 32 + tx;
        const int blk = blockIdx.y * 32 + blockIdx.x;      // 0..127
        const int R0 = blk * 16;
        #pragma unroll
        for (int i = 0; i < 8; ++i) {
            const int f = t + 256 * i;
            ds[f >> 7][f & 127] = dec[(size_t)R0 * H_ + f];
        }
        __syncthreads();
        const int k = t & 127, dd = t >> 7;
        const float* wr = Ww + (size_t)k * H_;
        float s[8];
        #pragma unroll
        for (int j = 0; j < 8; ++j) s[j] = 0.f;
        for (int h = 0; h < H_; h += 4) {
            const float4 w4 = *(const float4*)(wr + h);
            #pragma unroll
            for (int j = 0; j < 8; ++j) {
                const float4 d4 = *(const float4*)&ds[dd + 2 * j][h];
                s[j] = fmaf(w4.x, d4.x, s[j]);
                s[j] = fmaf(w4.y, d4.y, s[j]);
                s[j] = fmaf(w4.z, d4.z, s[j]);
                s[j] = fmaf(w4.w, d4.w, s[j]);
            }
        }
        const float wb = Wb[k], vw = Vw[k];
        const int g = k >> 2, jj = k & 3;
        #pragma unroll
        for (int j = 0; j < 8; ++j) {
            const int rl = dd + 2 * j;          // row within 16-row block
            const int R = R0 + rl;
            const float ea = __expf(2.f * (s[j] + wb));
            // h-major, d-minor: enables packed d-pair math in the fused kernel
            g_eav[((size_t)(R >> 2) * 32 + g) * 20 + 4 + jj * 4 + (R & 3)] = ea;
        }
        if (dd == 0) {
            #pragma unroll
            for (int r = 0; r < 4; ++r)
                g_eav[((size_t)((R0 >> 2) + r) * 32 + g) * 20 + jj] = vw;
        }
        if (blk == 0) {
            __shared__ float svp[2];
            if (t < 128) {
                float x = vw;
                #pragma unroll
                for (int off = 32; off; off >>= 1) x += __shfl_xor(x, off);
                if ((t & 63) == 0) svp[t >> 6] = x;
            }
            __syncthreads();
            if (t == 0) g_sv[0] = svp[0] + svp[1];
        }
    }
}

// Packed 4-h fraction combine over a d-pair: one VOP3P op per step,
// 2 scalar rcp.  sum_i V_i/p_i = [ (V1 p0 + V0 p1) p2 p3 + (V3 p2 + V2 p3) p0 p1 ] / prod
__device__ __forceinline__ f2 term4p(f2 p0, f2 p1, f2 p2, f2 p3,
                                     const float4 v4, f2 acc) {
    const f2 q01 = p0 * p1, q23 = p2 * p3;
    const f2 a   = __builtin_elementwise_fma(bc(v4.y), p0, bc(v4.x) * p1);
    const f2 bq  = __builtin_elementwise_fma(bc(v4.w), p2, bc(v4.z) * p3);
    const f2 num = __builtin_elementwise_fma(bq, q01, a * q23);
    const f2 den = q01 * q23;
    f2 r;
    r.x = __builtin_amdgcn_rcpf(den.x);
    r.y = __builtin_amdgcn_rcpf(den.y);
    return __builtin_elementwise_fma(num, r, acc);
}

// Both d-pairs for one g (4 h-planes), te given as 4 scalars.
#define DALLP(S, t0, t1, t2, t3) do {                                          \
    const f2 one2 = {1.f, 1.f};                                                \
    f2 pA0 = __builtin_elementwise_fma(S.hd[0], bc(t0), one2);                 \
    f2 pB0 = __builtin_elementwise_fma(S.hd[1], bc(t0), one2);                 \
    f2 pA1 = __builtin_elementwise_fma(S.hd[2], bc(t1), one2);                 \
    f2 pB1 = __builtin_elementwise_fma(S.hd[3], bc(t1), one2);                 \
    f2 pA2 = __builtin_elementwise_fma(S.hd[4], bc(t2), one2);                 \
    f2 pB2 = __builtin_elementwise_fma(S.hd[5], bc(t2), one2);                 \
    f2 pA3 = __builtin_elementwise_fma(S.hd[6], bc(t3), one2);                 \
    f2 pB3 = __builtin_elementwise_fma(S.hd[7], bc(t3), one2);                 \
    acc01 = term4p(pA0, pA1, pA2, pA3, S.v4, acc01);                           \
    acc23 = term4p(pB0, pB1, pB2, pB3, S.v4, acc23);                           \
} while (0)

// Fused: score + softmax(sum-only) + context + write.  Block = 1 row-tile
// (4 rows), 1024 threads (thread owns 1 e); grid 512, XCD-swizzled.
// Phase 1: fp16x8 te loads (16 events), packed dual-FP32 math over d-pairs.
__global__ __launch_bounds__(1024, 8) void fused_kernel(float* __restrict__ out) {
    __shared__ float sc[DT][TENC];          // p = exp(score)      (16 KB)
    __shared__ f2 part[16][DT][64];         // context partials    (32 KB)
    __shared__ float wsum[16][DT];
    __shared__ float rsum[DT];

    const int t = threadIdx.x;
    // XCD-locality swizzle: XCD x (= bid%8) gets contiguous row-tiles
    const int bid = blockIdx.x;
    const int rt = (bid & 7) * 64 + (bid >> 3);
    const int b = rt >> 7;
    const int R0 = rt * DT;
    const EAVP* epk = (const EAVP*)g_eav + (size_t)rt * 32;
    const _Float16* teb = g_ebp + (size_t)b * 16 * TENC * 8 + t * 8;
    const float sv = g_sv[0];

    // --- Phase 1: scores; 16 load events, packed math (2 g per load) ---
    f2 acc01 = {0.f, 0.f}, acc23 = {0.f, 0.f};

    for (int gp = 0; gp < 16; ++gp) {
        H8 r;
        r.v = *(const float4*)(teb + (size_t)gp * (TENC * 8));
        const float t0 = (float)r.h[0], t1 = (float)r.h[1];
        const float t2 = (float)r.h[2], t3 = (float)r.h[3];
        const float t4 = (float)r.h[4], t5 = (float)r.h[5];
        const float t6 = (float)r.h[6], t7 = (float)r.h[7];
        const EAVP A  = epk[2 * gp];
        const EAVP Bv = epk[2 * gp + 1];
        DALLP(A, t0, t1, t2, t3);
        DALLP(Bv, t4, t5, t6, t7);
    }

    // --- Phase 2: p = exp(score); stash + per-wave partial sums ---
    const float q0 = __expf(fmaf(-2.f, acc01.x, sv));
    const float q1 = __expf(fmaf(-2.f, acc01.y, sv));
    const float q2 = __expf(fmaf(-2.f, acc23.x, sv));
    const float q3 = __expf(fmaf(-2.f, acc23.y, sv));
    sc[0][t] = q0; sc[1][t] = q1; sc[2][t] = q2; sc[3][t] = q3;

    float s0 = q0, s1 = q1, s2 = q2, s3 = q3;
    #pragma unroll
    for (int off = 32; off; off >>= 1) {
        s0 += __shfl_xor(s0, off);
        s1 += __shfl_xor(s1, off);
        s2 += __shfl_xor(s2, off);
        s3 += __shfl_xor(s3, off);
    }
    {
        const int w = t >> 6, lane = t & 63;
        if (lane == 0) { wsum[w][0] = s0; wsum[w][1] = s1; wsum[w][2] = s2; wsum[w][3] = s3; }
    }
    __syncthreads();
    if (t < 64) {                            // lane = w'*4 + d
        float x = wsum[t >> 2][t & 3];
        #pragma unroll
        for (int off = 4; off < 64; off <<= 1) x += __shfl_xor(x, off);
        if (t < 4) rsum[t] = x;
    }

    // --- Phase 3: context partials from fp16 enc; packed (x,y) h-pair math ---
    {
        const int q = t >> 6, h2 = t & 63;
        const _Float16* eb = g_ench + (size_t)b * TENC * H_ + 2 * h2;
        f2 a0 = {0.f, 0.f}, a1 = {0.f, 0.f}, a2 = {0.f, 0.f}, a3 = {0.f, 0.f};
        const int e0 = q * 64;
        for (int e = e0; e < e0 + 64; e += 4) {
            F4 u0, u1, u2, u3;
            u0.v = *(const float4*)&sc[0][e];
            u1.v = *(const float4*)&sc[1][e];
            u2.v = *(const float4*)&sc[2][e];
            u3.v = *(const float4*)&sc[3][e];
            #pragma unroll
            for (int j = 0; j < 4; ++j) {
                H2 hv; hv.u = *(const unsigned int*)(eb + (size_t)(e + j) * H_);
                f2 ev; ev.x = (float)hv.h[0]; ev.y = (float)hv.h[1];
                a0 = __builtin_elementwise_fma(bc(u0.f[j]), ev, a0);
                a1 = __builtin_elementwise_fma(bc(u1.f[j]), ev, a1);
                a2 = __builtin_elementwise_fma(bc(u2.f[j]), ev, a2);
                a3 = __builtin_elementwise_fma(bc(u3.f[j]), ev, a3);
            }
        }
        part[q][0][h2] = a0; part[q][1][h2] = a1;
        part[q][2][h2] = a2; part[q][3][h2] = a3;
    }
    __syncthreads();

    // --- Phase 4: merge 16 slices, divide, write ---
    if (t < 256) {
        const int d = t >> 6, h2 = t & 63;
        f2 s = {0.f, 0.f};
        #pragma unroll
        for (int q = 0; q < 16; ++q) s += part[q][d][h2];
        const float rinv = __builtin_amdgcn_rcpf(rsum[d]);
        s *= bc(rinv);
        *(f2*)(out + (size_t)(R0 + d) * H_ + 2 * h2) = s;
    }
}

extern "C" void kernel_launch(void* const* d_in, const int* in_sizes, int n_in,
                              void* d_out, int out_size, void* d_ws, size_t ws_size,
                              hipStream_t stream) {
    const float* dec = (const float*)d_in[0];
    const float* enc = (const float*)d_in[1];
    const float* Ww  = (const float*)d_in[2];
    const float* Wb  = (const float*)d_in[3];
    const float* Vw  = (const float*)d_in[4];
    float* out = (float*)d_out;

    prep_kernel<<<dim3(TENC / 32, H_ / 32, B_ + 1), dim3(32, 8), 0, stream>>>(
        enc, dec, Ww, Wb, Vw);
    fused_kernel<<<dim3(B_ * 128), dim3(1024), 0, stream>>>(out);
}